// Round 2
// baseline (212.756 us; speedup 1.0000x reference)
//
#include <hip/hip_runtime.h>
#include <hip/hip_bf16.h>
#include <stdint.h>

using f32x4  = __attribute__((ext_vector_type(4))) float;
using bf16x8 = __attribute__((ext_vector_type(8))) short;

#define DEVINL static __device__ __forceinline__

DEVINL short f2bf(float f) {
    union { float f; uint32_t u; } v; v.f = f;
    uint32_t r = (v.u + 0x7FFFu + ((v.u >> 16) & 1u)) >> 16;   // RNE
    return (short)(uint16_t)r;
}
DEVINL float bf2f(short s) {
    union { uint32_t u; float f; } v; v.u = ((uint32_t)(uint16_t)s) << 16;
    return v.f;
}

// ---------------- K0: weight prep (fp32 -> bf16, stack Wg|Wt|Wp) ----------------
__global__ __launch_bounds__(256) void k0_prep(
        const float* __restrict__ Wg, const float* __restrict__ Wt, const float* __restrict__ Wp,
        const float* __restrict__ bg, const float* __restrict__ bt, const float* __restrict__ bp,
        const float* __restrict__ Ww,
        short* __restrict__ W_all, short* __restrict__ Ww16, float* __restrict__ b_all) {
    int i = blockIdx.x * 256 + threadIdx.x;
    if (i < 384 * 256) {
        int r = i >> 8, c = i & 255;
        float v = (r < 128) ? Wg[r * 256 + c] : (r < 256) ? Wt[(r - 128) * 256 + c] : Wp[(r - 256) * 256 + c];
        W_all[i] = f2bf(v);
    } else if (i < 384 * 256 + 256 * 128) {
        int j = i - 384 * 256;
        Ww16[j] = f2bf(Ww[j]);
    }
    if (i < 384) {
        b_all[i] = (i < 128) ? bg[i] : (i < 256) ? bt[i - 128] : bp[i - 256];
    }
}

// ---------------- K1: fused conv1x1 x3 GEMM ----------------
// Out[b][n][o] (o in [0,384): 0..127=g, 128..255=theta, 256..383=phi), bf16
__global__ __launch_bounds__(256) void k1_conv(const float* __restrict__ x,
        const short* __restrict__ W_all, const float* __restrict__ b_all,
        short* __restrict__ Out) {
    __shared__ short xs[128 * 40];          // [n(128)][c(32)+pad8]
    const int ntile = blockIdx.x;           // 32
    const int otile = blockIdx.y;           // 3
    const int b     = blockIdx.z;           // 8
    const int tid  = threadIdx.x;
    const int lane = tid & 63;
    const int wave = tid >> 6;
    const int wn = wave >> 1, wo = wave & 1;
    const int l15 = lane & 15, lh = lane >> 4;

    f32x4 acc[4][4];
    #pragma unroll
    for (int i = 0; i < 4; i++)
        #pragma unroll
        for (int j = 0; j < 4; j++) acc[i][j] = f32x4{0.f, 0.f, 0.f, 0.f};

    const int n0 = ntile * 128;
    const int ob = otile * 128 + wo * 64;
    const float* xb = x + (size_t)b * 256 * 4096;

    for (int kt = 0; kt < 8; kt++) {
        __syncthreads();
        #pragma unroll
        for (int p = 0; p < 4; p++) {
            int c  = p * 8 + (tid >> 5);
            int n4 = (tid & 31) * 4;
            const float4 v = *(const float4*)(xb + (size_t)(kt * 32 + c) * 4096 + n0 + n4);
            xs[(n4 + 0) * 40 + c] = f2bf(v.x);
            xs[(n4 + 1) * 40 + c] = f2bf(v.y);
            xs[(n4 + 2) * 40 + c] = f2bf(v.z);
            xs[(n4 + 3) * 40 + c] = f2bf(v.w);
        }
        __syncthreads();

        bf16x8 a[4], w[4];
        #pragma unroll
        for (int nf = 0; nf < 4; nf++)
            a[nf] = *(const bf16x8*)&xs[(wn * 64 + nf * 16 + l15) * 40 + lh * 8];
        #pragma unroll
        for (int of = 0; of < 4; of++)
            w[of] = *(const bf16x8*)(W_all + (size_t)(ob + of * 16 + l15) * 256 + kt * 32 + lh * 8);
        #pragma unroll
        for (int nf = 0; nf < 4; nf++)
            #pragma unroll
            for (int of = 0; of < 4; of++)
                acc[nf][of] = __builtin_amdgcn_mfma_f32_16x16x32_bf16(a[nf], w[of], acc[nf][of], 0, 0, 0);
    }

    #pragma unroll
    for (int of = 0; of < 4; of++) {
        int o = ob + of * 16 + l15;
        float bias = b_all[o];
        #pragma unroll
        for (int nf = 0; nf < 4; nf++)
            #pragma unroll
            for (int r = 0; r < 4; r++) {
                int n = n0 + wn * 64 + nf * 16 + lh * 4 + r;
                Out[((size_t)b * 4096 + n) * 384 + o] = f2bf(acc[nf][of][r] + bias);
            }
    }
}

// ---------------- K2a: maxpool phi -> Kmat[b][m][c] (bf16) ----------------
__global__ __launch_bounds__(256) void k2a_poolK(const short* __restrict__ Out, short* __restrict__ Kmat) {
    int t = blockIdx.x * 256 + threadIdx.x;
    int c8 = t & 15;
    int m  = (t >> 4) & 1023;
    int b  = t >> 14;
    int hp = m >> 5, wp = m & 31;
    int n0 = hp * 128 + wp * 2;
    const short* base = Out + (size_t)b * 4096 * 384 + 256 + c8 * 8;
    bf16x8 v0 = *(const bf16x8*)(base + (size_t)(n0) * 384);
    bf16x8 v1 = *(const bf16x8*)(base + (size_t)(n0 + 1) * 384);
    bf16x8 v2 = *(const bf16x8*)(base + (size_t)(n0 + 64) * 384);
    bf16x8 v3 = *(const bf16x8*)(base + (size_t)(n0 + 65) * 384);
    bf16x8 vo;
    #pragma unroll
    for (int i = 0; i < 8; i++) {
        float mx = fmaxf(fmaxf(bf2f(v0[i]), bf2f(v1[i])), fmaxf(bf2f(v2[i]), bf2f(v3[i])));
        vo[i] = f2bf(mx);
    }
    *(bf16x8*)(Kmat + ((size_t)b * 1024 + m) * 128 + c8 * 8) = vo;
}

// ---------------- K2b: maxpool g -> Vmat[b][c][m] (bf16, transposed) ----------------
__global__ __launch_bounds__(256) void k2b_poolV(const short* __restrict__ Out, short* __restrict__ Vmat) {
    __shared__ short g[128 * 136];
    int b  = blockIdx.x >> 5;
    int hp = blockIdx.x & 31;
    int tid = threadIdx.x;
    {
        int nloc = tid >> 1;
        int ch0  = (tid & 1) * 8;
        const short* src = Out + ((size_t)b * 4096 + hp * 128 + nloc) * 384;
        #pragma unroll
        for (int i = 0; i < 8; i++) {
            int chunk = ch0 + i;
            *(bf16x8*)&g[nloc * 136 + chunk * 8] = *(const bf16x8*)(src + chunk * 8);
        }
    }
    __syncthreads();
    int wp = tid & 31;
    int cb = tid >> 5;
    #pragma unroll
    for (int pass = 0; pass < 16; pass++) {
        int c = pass * 8 + cb;
        float a0 = bf2f(g[(2 * wp) * 136 + c]);
        float a1 = bf2f(g[(2 * wp + 1) * 136 + c]);
        float a2 = bf2f(g[(64 + 2 * wp) * 136 + c]);
        float a3 = bf2f(g[(65 + 2 * wp) * 136 + c]);
        float mx = fmaxf(fmaxf(a0, a1), fmaxf(a2, a3));
        Vmat[((size_t)b * 128 + c) * 1024 + hp * 32 + wp] = f2bf(mx);
    }
}

// ---------------- K3: flash attention v2 ----------------
// No barriers. 16 q-rows per wave, m-tile 128, K/V direct from global (L2-resident).
// b = blockIdx.x & 7 so each XCD's L2 serves one batch's K/V.
__global__ __launch_bounds__(256) void k3_attn(const short* __restrict__ Out,
        const short* __restrict__ Kmat, const short* __restrict__ Vmat,
        short* __restrict__ Ybuf) {
    __shared__ short sP[4][16 * 128];   // per-wave P, XOR-swizzled 8-short chunks

    const int bid = blockIdx.x;         // 512
    const int b   = bid & 7;
    const int nt  = bid >> 3;           // 64 tiles of 64 rows
    const int tid = threadIdx.x;
    const int lane = tid & 63;
    const int wave = tid >> 6;
    const int l15 = lane & 15, lh = lane >> 4;
    const int n0 = nt * 64 + wave * 16;

    const short* Kb = Kmat + (size_t)b * 1024 * 128;
    const short* Vb = Vmat + (size_t)b * 128 * 1024;
    short* sPw = sP[wave];

    bf16x8 q[4];
    {
        const short* qrow = Out + ((size_t)b * 4096 + n0 + l15) * 384 + 128;
        #pragma unroll
        for (int ks = 0; ks < 4; ks++)
            q[ks] = *(const bf16x8*)(qrow + ks * 32 + lh * 8);
    }

    f32x4 y[8];
    #pragma unroll
    for (int cf = 0; cf < 8; cf++) y[cf] = f32x4{0.f, 0.f, 0.f, 0.f};
    float mrun[4], lrun[4];
    #pragma unroll
    for (int r = 0; r < 4; r++) { mrun[r] = -1e30f; lrun[r] = 0.f; }

    for (int t = 0; t < 8; t++) {
        const int m0 = t * 128;

        // S = Q K^T over a 128-wide m tile
        f32x4 S[8];
        #pragma unroll
        for (int mf = 0; mf < 8; mf++) S[mf] = f32x4{0.f, 0.f, 0.f, 0.f};
        #pragma unroll
        for (int ks = 0; ks < 4; ks++) {
            bf16x8 kf[8];
            #pragma unroll
            for (int mf = 0; mf < 8; mf++)
                kf[mf] = *(const bf16x8*)(Kb + (size_t)(m0 + mf * 16 + l15) * 128 + ks * 32 + lh * 8);
            #pragma unroll
            for (int mf = 0; mf < 8; mf++)
                S[mf] = __builtin_amdgcn_mfma_f32_16x16x32_bf16(q[ks], kf[mf], S[mf], 0, 0, 0);
        }

        // online softmax (reduce over 8 frags + 16 lanes)
        #pragma unroll
        for (int r = 0; r < 4; r++) {
            float v = fmaxf(fmaxf(fmaxf(S[0][r], S[1][r]), fmaxf(S[2][r], S[3][r])),
                            fmaxf(fmaxf(S[4][r], S[5][r]), fmaxf(S[6][r], S[7][r])));
            #pragma unroll
            for (int off = 1; off < 16; off <<= 1) v = fmaxf(v, __shfl_xor(v, off));
            float mnew  = fmaxf(mrun[r], v);
            float alpha = __expf(mrun[r] - mnew);
            mrun[r] = mnew;
            #pragma unroll
            for (int cf = 0; cf < 8; cf++) y[cf][r] *= alpha;
            float rs = 0.f;
            #pragma unroll
            for (int mf = 0; mf < 8; mf++) {
                float p = __expf(S[mf][r] - mnew);
                S[mf][r] = p;
                rs += p;
            }
            #pragma unroll
            for (int off = 1; off < 16; off <<= 1) rs += __shfl_xor(rs, off);
            lrun[r] = lrun[r] * alpha + rs;
        }

        // P (C-layout) -> per-wave LDS (A-layout), bf16, chunk XOR row swizzle
        #pragma unroll
        for (int mf = 0; mf < 8; mf++)
            #pragma unroll
            for (int r = 0; r < 4; r++) {
                int row   = lh * 4 + r;
                int chunk = mf * 2 + (l15 >> 3);
                sPw[row * 128 + ((chunk ^ row) * 8) + (l15 & 7)] = f2bf(S[mf][r]);
            }

        // y += P @ V^T  (V fragments direct from global)
        #pragma unroll
        for (int ks2 = 0; ks2 < 4; ks2++) {
            int jj = ks2 * 4 + lh;
            bf16x8 pa = *(const bf16x8*)&sPw[l15 * 128 + ((jj ^ l15) * 8)];
            #pragma unroll
            for (int cf = 0; cf < 8; cf++) {
                bf16x8 vf = *(const bf16x8*)(Vb + (size_t)(cf * 16 + l15) * 1024 + m0 + ks2 * 32 + lh * 8);
                y[cf] = __builtin_amdgcn_mfma_f32_16x16x32_bf16(pa, vf, y[cf], 0, 0, 0);
            }
        }
    }

    // epilogue
    float inv[4];
    #pragma unroll
    for (int r = 0; r < 4; r++) inv[r] = 1.f / lrun[r];
    #pragma unroll
    for (int cf = 0; cf < 8; cf++) {
        int c = cf * 16 + l15;
        #pragma unroll
        for (int r = 0; r < 4; r++)
            Ybuf[((size_t)b * 4096 + n0 + lh * 4 + r) * 128 + c] = f2bf(y[cf][r] * inv[r]);
    }
}

// ---------------- K4: wy = Ww @ y^T (+bias) + BN partial stats ----------------
// wy[b][o][n] bf16; stats[o*2]=sum, stats[o*2+1]=sumsq (atomic, fp32)
__global__ __launch_bounds__(256) void k4_wy(const short* __restrict__ Ww16,
        const short* __restrict__ Ybuf, const float* __restrict__ bw,
        short* __restrict__ wy, float* __restrict__ stats) {
    __shared__ float sums[4][64][2];
    const int nt = blockIdx.x;     // 16
    const int ot = blockIdx.y;     // 4
    const int b  = blockIdx.z;
    const int tid = threadIdx.x;
    const int lane = tid & 63, wave = tid >> 6;
    const int l15 = lane & 15, lh = lane >> 4;
    const int ob = ot * 64;
    const int nb = nt * 256 + wave * 64;

    bf16x8 aw[4][4];
    #pragma unroll
    for (int of = 0; of < 4; of++)
        #pragma unroll
        for (int ks = 0; ks < 4; ks++)
            aw[of][ks] = *(const bf16x8*)(Ww16 + (size_t)(ob + of * 16 + l15) * 128 + ks * 32 + lh * 8);

    f32x4 acc[4][4];               // [of][nf]
    #pragma unroll
    for (int i = 0; i < 4; i++)
        #pragma unroll
        for (int j = 0; j < 4; j++) acc[i][j] = f32x4{0.f, 0.f, 0.f, 0.f};

    #pragma unroll
    for (int nf = 0; nf < 4; nf++) {
        bf16x8 by[4];
        #pragma unroll
        for (int ks = 0; ks < 4; ks++)
            by[ks] = *(const bf16x8*)(Ybuf + ((size_t)b * 4096 + nb + nf * 16 + l15) * 128 + ks * 32 + lh * 8);
        #pragma unroll
        for (int of = 0; of < 4; of++)
            #pragma unroll
            for (int ks = 0; ks < 4; ks++)
                acc[of][nf] = __builtin_amdgcn_mfma_f32_16x16x32_bf16(aw[of][ks], by[ks], acc[of][nf], 0, 0, 0);
    }

    #pragma unroll
    for (int of = 0; of < 4; of++) {
        #pragma unroll
        for (int r = 0; r < 4; r++) {
            int o = ob + of * 16 + lh * 4 + r;
            float bias = bw[o];
            float s = 0.f, s2 = 0.f;
            #pragma unroll
            for (int nf = 0; nf < 4; nf++) {
                float v = acc[of][nf][r] + bias;
                wy[((size_t)b * 256 + o) * 4096 + nb + nf * 16 + l15] = f2bf(v);
                s += v; s2 += v * v;
            }
            #pragma unroll
            for (int off = 1; off < 16; off <<= 1) { s += __shfl_xor(s, off); s2 += __shfl_xor(s2, off); }
            if (l15 == 0) {
                sums[wave][of * 16 + lh * 4 + r][0] = s;
                sums[wave][of * 16 + lh * 4 + r][1] = s2;
            }
        }
    }
    __syncthreads();
    if (tid < 64) {
        float s  = sums[0][tid][0] + sums[1][tid][0] + sums[2][tid][0] + sums[3][tid][0];
        float s2 = sums[0][tid][1] + sums[1][tid][1] + sums[2][tid][1] + sums[3][tid][1];
        atomicAdd(&stats[(ob + tid) * 2], s);
        atomicAdd(&stats[(ob + tid) * 2 + 1], s2);
    }
}

// ---------------- K4b: finalize mean / rstd ----------------
__global__ __launch_bounds__(256) void k4b_stats(const float* __restrict__ stats, float* __restrict__ ms) {
    int o = threadIdx.x;
    float mean = stats[o * 2] * (1.f / 32768.f);
    float var  = stats[o * 2 + 1] * (1.f / 32768.f) - mean * mean;
    ms[o * 2] = mean;
    ms[o * 2 + 1] = rsqrtf(var + 1e-5f);
}

// ---------------- K5: BN apply + residual + global spatial max ----------------
__global__ __launch_bounds__(256) void k5_bnmax(const short* __restrict__ wy,
        const float* __restrict__ x, const float* __restrict__ ms,
        const float* __restrict__ gamma, const float* __restrict__ beta,
        float* __restrict__ outp) {
    int b = blockIdx.x >> 8;
    int o = blockIdx.x & 255;
    int tid = threadIdx.x;
    float mean = ms[o * 2], rstd = ms[o * 2 + 1];
    float A = rstd * gamma[o];
    float B = beta[o] - mean * A;
    const short* pw = wy + ((size_t)b * 256 + o) * 4096;
    const float* px = x + ((size_t)b * 256 + o) * 4096;
    float mx = -1e30f;
    #pragma unroll
    for (int j = 0; j < 2; j++) {
        int e = (tid + j * 256) * 8;
        bf16x8 w8 = *(const bf16x8*)(pw + e);
        float4 xa = *(const float4*)(px + e);
        float4 xb = *(const float4*)(px + e + 4);
        mx = fmaxf(mx, bf2f(w8[0]) * A + B + xa.x);
        mx = fmaxf(mx, bf2f(w8[1]) * A + B + xa.y);
        mx = fmaxf(mx, bf2f(w8[2]) * A + B + xa.z);
        mx = fmaxf(mx, bf2f(w8[3]) * A + B + xa.w);
        mx = fmaxf(mx, bf2f(w8[4]) * A + B + xb.x);
        mx = fmaxf(mx, bf2f(w8[5]) * A + B + xb.y);
        mx = fmaxf(mx, bf2f(w8[6]) * A + B + xb.z);
        mx = fmaxf(mx, bf2f(w8[7]) * A + B + xb.w);
    }
    #pragma unroll
    for (int off = 1; off < 64; off <<= 1) mx = fmaxf(mx, __shfl_xor(mx, off));
    __shared__ float red[4];
    if ((tid & 63) == 0) red[tid >> 6] = mx;
    __syncthreads();
    if (tid == 0)
        outp[b * 256 + o] = fmaxf(fmaxf(red[0], red[1]), fmaxf(red[2], red[3]));
}

extern "C" void kernel_launch(void* const* d_in, const int* in_sizes, int n_in,
                              void* d_out, int out_size, void* d_ws, size_t ws_size,
                              hipStream_t stream) {
    const float* x     = (const float*)d_in[0];
    const float* Wg    = (const float*)d_in[1];
    const float* bg    = (const float*)d_in[2];
    const float* Wt    = (const float*)d_in[3];
    const float* bt    = (const float*)d_in[4];
    const float* Wp    = (const float*)d_in[5];
    const float* bp    = (const float*)d_in[6];
    const float* Ww    = (const float*)d_in[7];
    const float* bw    = (const float*)d_in[8];
    const float* gamma = (const float*)d_in[9];
    const float* beta  = (const float*)d_in[10];
    float* outp = (float*)d_out;

    char* ws = (char*)d_ws;
    size_t off = 0;
    auto alloc = [&](size_t bytes) -> void* {
        void* p = ws + off;
        off = (off + bytes + 255) & ~(size_t)255;
        return p;
    };
    short* W_all = (short*)alloc((size_t)384 * 256 * 2);
    short* Ww16  = (short*)alloc((size_t)256 * 128 * 2);
    float* b_all = (float*)alloc((size_t)384 * 4);
    short* Out   = (short*)alloc((size_t)8 * 4096 * 384 * 2);
    short* Kmat  = (short*)alloc((size_t)8 * 1024 * 128 * 2);
    short* Vmat  = (short*)alloc((size_t)8 * 128 * 1024 * 2);
    short* Ybuf  = (short*)alloc((size_t)8 * 4096 * 128 * 2);
    short* wy    = (short*)alloc((size_t)8 * 256 * 4096 * 2);
    float* stats = (float*)alloc((size_t)256 * 2 * 4);
    float* ms    = (float*)alloc((size_t)256 * 2 * 4);

    hipMemsetAsync(stats, 0, 256 * 2 * 4, stream);

    k0_prep<<<512, 256, 0, stream>>>(Wg, Wt, Wp, bg, bt, bp, Ww, W_all, Ww16, b_all);
    k1_conv<<<dim3(32, 3, 8), 256, 0, stream>>>(x, W_all, b_all, Out);
    k2a_poolK<<<512, 256, 0, stream>>>(Out, Kmat);
    k2b_poolV<<<256, 256, 0, stream>>>(Out, Vmat);
    k3_attn<<<512, 256, 0, stream>>>(Out, Kmat, Vmat, Ybuf);
    k4_wy<<<dim3(16, 4, 8), 256, 0, stream>>>(Ww16, Ybuf, bw, wy, stats);
    k4b_stats<<<1, 256, 0, stream>>>(stats, ms);
    k5_bnmax<<<2048, 256, 0, stream>>>(wy, x, ms, gamma, beta, outp);
}

// Round 3
// 135.881 us; speedup vs baseline: 1.5658x; 1.5658x over previous
//
#include <hip/hip_runtime.h>
#include <hip/hip_bf16.h>
#include <stdint.h>

using f32x4  = __attribute__((ext_vector_type(4))) float;
using bf16x8 = __attribute__((ext_vector_type(8))) short;

#define DEVINL static __device__ __forceinline__

DEVINL short f2bf(float f) {
    union { float f; uint32_t u; } v; v.f = f;
    uint32_t r = (v.u + 0x7FFFu + ((v.u >> 16) & 1u)) >> 16;   // RNE
    return (short)(uint16_t)r;
}
DEVINL float bf2f(short s) {
    union { uint32_t u; float f; } v; v.u = ((uint32_t)(uint16_t)s) << 16;
    return v.f;
}

// async global -> LDS, 16B per lane. LDS dest must be wave-uniform base (+lane*16 by HW).
DEVINL void gld16(const short* g, short* l) {
    __builtin_amdgcn_global_load_lds(
        (const __attribute__((address_space(1))) unsigned int*)g,
        (__attribute__((address_space(3))) unsigned int*)l, 16, 0, 0);
}

// ---------------- K0: weight prep (fp32 -> bf16, stack Wg|Wt|Wp) ----------------
__global__ __launch_bounds__(256) void k0_prep(
        const float* __restrict__ Wg, const float* __restrict__ Wt, const float* __restrict__ Wp,
        const float* __restrict__ bg, const float* __restrict__ bt, const float* __restrict__ bp,
        const float* __restrict__ Ww,
        short* __restrict__ W_all, short* __restrict__ Ww16, float* __restrict__ b_all) {
    int i = blockIdx.x * 256 + threadIdx.x;
    if (i < 384 * 256) {
        int r = i >> 8, c = i & 255;
        float v = (r < 128) ? Wg[r * 256 + c] : (r < 256) ? Wt[(r - 128) * 256 + c] : Wp[(r - 256) * 256 + c];
        W_all[i] = f2bf(v);
    } else if (i < 384 * 256 + 256 * 128) {
        int j = i - 384 * 256;
        Ww16[j] = f2bf(Ww[j]);
    }
    if (i < 384) {
        b_all[i] = (i < 128) ? bg[i] : (i < 256) ? bt[i - 128] : bp[i - 256];
    }
}

// ---------------- K1: fused conv1x1 x3 GEMM ----------------
// Out[b][n][o] (o in [0,384): 0..127=g, 128..255=theta, 256..383=phi), bf16
__global__ __launch_bounds__(256) void k1_conv(const float* __restrict__ x,
        const short* __restrict__ W_all, const float* __restrict__ b_all,
        short* __restrict__ Out) {
    __shared__ short xs[128 * 40];          // [n(128)][c(32)+pad8]
    const int ntile = blockIdx.x;           // 32
    const int otile = blockIdx.y;           // 3
    const int b     = blockIdx.z;           // 8
    const int tid  = threadIdx.x;
    const int lane = tid & 63;
    const int wave = tid >> 6;
    const int wn = wave >> 1, wo = wave & 1;
    const int l15 = lane & 15, lh = lane >> 4;

    f32x4 acc[4][4];
    #pragma unroll
    for (int i = 0; i < 4; i++)
        #pragma unroll
        for (int j = 0; j < 4; j++) acc[i][j] = f32x4{0.f, 0.f, 0.f, 0.f};

    const int n0 = ntile * 128;
    const int ob = otile * 128 + wo * 64;
    const float* xb = x + (size_t)b * 256 * 4096;

    for (int kt = 0; kt < 8; kt++) {
        __syncthreads();
        #pragma unroll
        for (int p = 0; p < 4; p++) {
            int c  = p * 8 + (tid >> 5);
            int n4 = (tid & 31) * 4;
            const float4 v = *(const float4*)(xb + (size_t)(kt * 32 + c) * 4096 + n0 + n4);
            xs[(n4 + 0) * 40 + c] = f2bf(v.x);
            xs[(n4 + 1) * 40 + c] = f2bf(v.y);
            xs[(n4 + 2) * 40 + c] = f2bf(v.z);
            xs[(n4 + 3) * 40 + c] = f2bf(v.w);
        }
        __syncthreads();

        bf16x8 a[4], w[4];
        #pragma unroll
        for (int nf = 0; nf < 4; nf++)
            a[nf] = *(const bf16x8*)&xs[(wn * 64 + nf * 16 + l15) * 40 + lh * 8];
        #pragma unroll
        for (int of = 0; of < 4; of++)
            w[of] = *(const bf16x8*)(W_all + (size_t)(ob + of * 16 + l15) * 256 + kt * 32 + lh * 8);
        #pragma unroll
        for (int nf = 0; nf < 4; nf++)
            #pragma unroll
            for (int of = 0; of < 4; of++)
                acc[nf][of] = __builtin_amdgcn_mfma_f32_16x16x32_bf16(a[nf], w[of], acc[nf][of], 0, 0, 0);
    }

    #pragma unroll
    for (int of = 0; of < 4; of++) {
        int o = ob + of * 16 + l15;
        float bias = b_all[o];
        #pragma unroll
        for (int nf = 0; nf < 4; nf++)
            #pragma unroll
            for (int r = 0; r < 4; r++) {
                int n = n0 + wn * 64 + nf * 16 + lh * 4 + r;
                Out[((size_t)b * 4096 + n) * 384 + o] = f2bf(acc[nf][of][r] + bias);
            }
    }
}

// ---------------- K2a: maxpool phi -> Kmat[b][m][c] (bf16) ----------------
__global__ __launch_bounds__(256) void k2a_poolK(const short* __restrict__ Out, short* __restrict__ Kmat) {
    int t = blockIdx.x * 256 + threadIdx.x;
    int c8 = t & 15;
    int m  = (t >> 4) & 1023;
    int b  = t >> 14;
    int hp = m >> 5, wp = m & 31;
    int n0 = hp * 128 + wp * 2;
    const short* base = Out + (size_t)b * 4096 * 384 + 256 + c8 * 8;
    bf16x8 v0 = *(const bf16x8*)(base + (size_t)(n0) * 384);
    bf16x8 v1 = *(const bf16x8*)(base + (size_t)(n0 + 1) * 384);
    bf16x8 v2 = *(const bf16x8*)(base + (size_t)(n0 + 64) * 384);
    bf16x8 v3 = *(const bf16x8*)(base + (size_t)(n0 + 65) * 384);
    bf16x8 vo;
    #pragma unroll
    for (int i = 0; i < 8; i++) {
        float mx = fmaxf(fmaxf(bf2f(v0[i]), bf2f(v1[i])), fmaxf(bf2f(v2[i]), bf2f(v3[i])));
        vo[i] = f2bf(mx);
    }
    *(bf16x8*)(Kmat + ((size_t)b * 1024 + m) * 128 + c8 * 8) = vo;
}

// ---------------- K2b: maxpool g -> Vmat[b][c][m] (bf16, transposed) ----------------
__global__ __launch_bounds__(256) void k2b_poolV(const short* __restrict__ Out, short* __restrict__ Vmat) {
    __shared__ short g[128 * 136];
    int b  = blockIdx.x >> 5;
    int hp = blockIdx.x & 31;
    int tid = threadIdx.x;
    {
        int nloc = tid >> 1;
        int ch0  = (tid & 1) * 8;
        const short* src = Out + ((size_t)b * 4096 + hp * 128 + nloc) * 384;
        #pragma unroll
        for (int i = 0; i < 8; i++) {
            int chunk = ch0 + i;
            *(bf16x8*)&g[nloc * 136 + chunk * 8] = *(const bf16x8*)(src + chunk * 8);
        }
    }
    __syncthreads();
    int wp = tid & 31;
    int cb = tid >> 5;
    #pragma unroll
    for (int pass = 0; pass < 16; pass++) {
        int c = pass * 8 + cb;
        float a0 = bf2f(g[(2 * wp) * 136 + c]);
        float a1 = bf2f(g[(2 * wp + 1) * 136 + c]);
        float a2 = bf2f(g[(64 + 2 * wp) * 136 + c]);
        float a3 = bf2f(g[(65 + 2 * wp) * 136 + c]);
        float mx = fmaxf(fmaxf(a0, a1), fmaxf(a2, a3));
        Vmat[((size_t)b * 128 + c) * 1024 + hp * 32 + wp] = f2bf(mx);
    }
}

// ---------------- K3: flash attention v3 ----------------
// LDS-staged K/V, double-buffered via global_load_lds(16B) with pre-swizzled source.
// 4 waves x 16 q-rows, m-tile 64, 2 blocks/CU. Defer-max online softmax.
__global__ __launch_bounds__(256) void k3_attn(const short* __restrict__ Out,
        const short* __restrict__ Kmat, const short* __restrict__ Vmat,
        short* __restrict__ Ybuf) {
    __shared__ short sK[2][64 * 128];   // [m][c], content chunk-XOR-swizzled by row
    __shared__ short sV[2][128 * 64];   // [c][m], content chunk-XOR-swizzled by row
    __shared__ short sP[4][16 * 64];    // per-wave P

    const int bid = blockIdx.x;         // 512
    const int b   = bid & 7;            // XCD swizzle: consecutive ids -> different XCDs, same-batch set on one XCD
    const int nt  = bid >> 3;           // 64 tiles of 64 rows
    const int tid = threadIdx.x;
    const int lane = tid & 63;
    const int wave = tid >> 6;
    const int l15 = lane & 15, lh = lane >> 4;
    const int n0 = nt * 64 + wave * 16;

    const short* Kb = Kmat + (size_t)b * 1024 * 128;
    const short* Vb = Vmat + (size_t)b * 128 * 1024;
    short* sPw = sP[wave];

    // stage one 64-wide m-tile (K: 64x128, V: 128x64) into buffer bufi
    auto STAGE = [&](int t, int bufi) {
        const int m0 = t * 64;
        #pragma unroll
        for (int i = 0; i < 4; i++) {
            const int segb = (i * 4 + wave) * 64;          // wave-uniform segment base
            const int rowK = (segb >> 4) + (lane >> 4);
            const int chkK = lane & 15;
            gld16(Kb + (size_t)(m0 + rowK) * 128 + ((chkK ^ (rowK & 15)) << 3),
                  &sK[bufi][segb * 8]);
            const int rowV = (segb >> 3) + (lane >> 3);
            const int chkV = lane & 7;
            gld16(Vb + (size_t)rowV * 1024 + m0 + ((chkV ^ (rowV & 7)) << 3),
                  &sV[bufi][segb * 8]);
        }
    };

    bf16x8 q[4];
    {
        const short* qrow = Out + ((size_t)b * 4096 + n0 + l15) * 384 + 128;
        #pragma unroll
        for (int ks = 0; ks < 4; ks++)
            q[ks] = *(const bf16x8*)(qrow + ks * 32 + lh * 8);
    }

    f32x4 y[8];
    #pragma unroll
    for (int cf = 0; cf < 8; cf++) y[cf] = f32x4{0.f, 0.f, 0.f, 0.f};
    float mrun[4], lrun[4];
    #pragma unroll
    for (int r = 0; r < 4; r++) { mrun[r] = -1e30f; lrun[r] = 0.f; }

    STAGE(0, 0);
    __syncthreads();
    int cur = 0;

    for (int t = 0; t < 16; t++) {
        if (t < 15) STAGE(t + 1, cur ^ 1);

        const short* cK = sK[cur];
        const short* cV = sV[cur];

        // S = Q K^T over 64-wide m tile
        f32x4 S[4];
        #pragma unroll
        for (int mf = 0; mf < 4; mf++) S[mf] = f32x4{0.f, 0.f, 0.f, 0.f};
        #pragma unroll
        for (int ks = 0; ks < 4; ks++) {
            bf16x8 kf[4];
            #pragma unroll
            for (int mf = 0; mf < 4; mf++) {
                int mrow = mf * 16 + l15;
                int jj   = ks * 4 + lh;
                kf[mf] = *(const bf16x8*)&cK[mrow * 128 + ((jj ^ (mrow & 15)) << 3)];
            }
            #pragma unroll
            for (int mf = 0; mf < 4; mf++)
                S[mf] = __builtin_amdgcn_mfma_f32_16x16x32_bf16(q[ks], kf[mf], S[mf], 0, 0, 0);
        }

        // online softmax with defer-max (rescale only when max grows by >6)
        float pm[4];
        #pragma unroll
        for (int r = 0; r < 4; r++) {
            float v = fmaxf(fmaxf(S[0][r], S[1][r]), fmaxf(S[2][r], S[3][r]));
            #pragma unroll
            for (int off = 1; off < 16; off <<= 1) v = fmaxf(v, __shfl_xor(v, off));
            pm[r] = v;
        }
        bool grow = (pm[0] > mrun[0] + 6.f) | (pm[1] > mrun[1] + 6.f) |
                    (pm[2] > mrun[2] + 6.f) | (pm[3] > mrun[3] + 6.f);
        if (__any(grow)) {
            #pragma unroll
            for (int r = 0; r < 4; r++) {
                float mnew  = fmaxf(mrun[r], pm[r]);
                float alpha = __expf(mrun[r] - mnew);
                mrun[r] = mnew;
                #pragma unroll
                for (int cf = 0; cf < 8; cf++) y[cf][r] *= alpha;
                lrun[r] *= alpha;
            }
        }
        #pragma unroll
        for (int r = 0; r < 4; r++) {
            float rs = 0.f;
            #pragma unroll
            for (int mf = 0; mf < 4; mf++) {
                float p = __expf(S[mf][r] - mrun[r]);
                S[mf][r] = p;
                rs += p;
            }
            #pragma unroll
            for (int off = 1; off < 16; off <<= 1) rs += __shfl_xor(rs, off);
            lrun[r] += rs;
        }

        // P (C-layout) -> per-wave LDS (A-layout), chunk-XOR swizzle
        #pragma unroll
        for (int mf = 0; mf < 4; mf++)
            #pragma unroll
            for (int r = 0; r < 4; r++) {
                int row = lh * 4 + r;
                int col = mf * 16 + l15;
                sPw[row * 64 + (((col >> 3) ^ (row & 7)) << 3) + (col & 7)] = f2bf(S[mf][r]);
            }

        // y += P @ V^T
        #pragma unroll
        for (int ks2 = 0; ks2 < 2; ks2++) {
            int jj = ks2 * 4 + lh;
            bf16x8 pa = *(const bf16x8*)&sPw[l15 * 64 + ((jj ^ (l15 & 7)) << 3)];
            #pragma unroll
            for (int cf = 0; cf < 8; cf++) {
                int crow = cf * 16 + l15;
                bf16x8 vf = *(const bf16x8*)&cV[crow * 64 + ((jj ^ (crow & 7)) << 3)];
                y[cf] = __builtin_amdgcn_mfma_f32_16x16x32_bf16(pa, vf, y[cf], 0, 0, 0);
            }
        }

        __syncthreads();
        cur ^= 1;
    }

    // epilogue
    float inv[4];
    #pragma unroll
    for (int r = 0; r < 4; r++) inv[r] = 1.f / lrun[r];
    #pragma unroll
    for (int cf = 0; cf < 8; cf++) {
        int c = cf * 16 + l15;
        #pragma unroll
        for (int r = 0; r < 4; r++)
            Ybuf[((size_t)b * 4096 + n0 + lh * 4 + r) * 128 + c] = f2bf(y[cf][r] * inv[r]);
    }
}

// ---------------- K4: wy = Ww @ y^T (+bias) + BN partial stats ----------------
// wy[b][o][n] bf16; stats[o*2]=sum, stats[o*2+1]=sumsq (atomic, fp32)
__global__ __launch_bounds__(256) void k4_wy(const short* __restrict__ Ww16,
        const short* __restrict__ Ybuf, const float* __restrict__ bw,
        short* __restrict__ wy, float* __restrict__ stats) {
    __shared__ float sums[4][64][2];
    const int nt = blockIdx.x;     // 16
    const int ot = blockIdx.y;     // 4
    const int b  = blockIdx.z;
    const int tid = threadIdx.x;
    const int lane = tid & 63, wave = tid >> 6;
    const int l15 = lane & 15, lh = lane >> 4;
    const int ob = ot * 64;
    const int nb = nt * 256 + wave * 64;

    bf16x8 aw[4][4];
    #pragma unroll
    for (int of = 0; of < 4; of++)
        #pragma unroll
        for (int ks = 0; ks < 4; ks++)
            aw[of][ks] = *(const bf16x8*)(Ww16 + (size_t)(ob + of * 16 + l15) * 128 + ks * 32 + lh * 8);

    f32x4 acc[4][4];               // [of][nf]
    #pragma unroll
    for (int i = 0; i < 4; i++)
        #pragma unroll
        for (int j = 0; j < 4; j++) acc[i][j] = f32x4{0.f, 0.f, 0.f, 0.f};

    #pragma unroll
    for (int nf = 0; nf < 4; nf++) {
        bf16x8 by[4];
        #pragma unroll
        for (int ks = 0; ks < 4; ks++)
            by[ks] = *(const bf16x8*)(Ybuf + ((size_t)b * 4096 + nb + nf * 16 + l15) * 128 + ks * 32 + lh * 8);
        #pragma unroll
        for (int of = 0; of < 4; of++)
            #pragma unroll
            for (int ks = 0; ks < 4; ks++)
                acc[of][nf] = __builtin_amdgcn_mfma_f32_16x16x32_bf16(aw[of][ks], by[ks], acc[of][nf], 0, 0, 0);
    }

    #pragma unroll
    for (int of = 0; of < 4; of++) {
        #pragma unroll
        for (int r = 0; r < 4; r++) {
            int o = ob + of * 16 + lh * 4 + r;
            float bias = bw[o];
            float s = 0.f, s2 = 0.f;
            #pragma unroll
            for (int nf = 0; nf < 4; nf++) {
                float v = acc[of][nf][r] + bias;
                wy[((size_t)b * 256 + o) * 4096 + nb + nf * 16 + l15] = f2bf(v);
                s += v; s2 += v * v;
            }
            #pragma unroll
            for (int off = 1; off < 16; off <<= 1) { s += __shfl_xor(s, off); s2 += __shfl_xor(s2, off); }
            if (l15 == 0) {
                sums[wave][of * 16 + lh * 4 + r][0] = s;
                sums[wave][of * 16 + lh * 4 + r][1] = s2;
            }
        }
    }
    __syncthreads();
    if (tid < 64) {
        float s  = sums[0][tid][0] + sums[1][tid][0] + sums[2][tid][0] + sums[3][tid][0];
        float s2 = sums[0][tid][1] + sums[1][tid][1] + sums[2][tid][1] + sums[3][tid][1];
        atomicAdd(&stats[(ob + tid) * 2], s);
        atomicAdd(&stats[(ob + tid) * 2 + 1], s2);
    }
}

// ---------------- K4b: finalize mean / rstd ----------------
__global__ __launch_bounds__(256) void k4b_stats(const float* __restrict__ stats, float* __restrict__ ms) {
    int o = threadIdx.x;
    float mean = stats[o * 2] * (1.f / 32768.f);
    float var  = stats[o * 2 + 1] * (1.f / 32768.f) - mean * mean;
    ms[o * 2] = mean;
    ms[o * 2 + 1] = rsqrtf(var + 1e-5f);
}

// ---------------- K5: BN apply + residual + global spatial max ----------------
__global__ __launch_bounds__(256) void k5_bnmax(const short* __restrict__ wy,
        const float* __restrict__ x, const float* __restrict__ ms,
        const float* __restrict__ gamma, const float* __restrict__ beta,
        float* __restrict__ outp) {
    int b = blockIdx.x >> 8;
    int o = blockIdx.x & 255;
    int tid = threadIdx.x;
    float mean = ms[o * 2], rstd = ms[o * 2 + 1];
    float A = rstd * gamma[o];
    float B = beta[o] - mean * A;
    const short* pw = wy + ((size_t)b * 256 + o) * 4096;
    const float* px = x + ((size_t)b * 256 + o) * 4096;
    float mx = -1e30f;
    #pragma unroll
    for (int j = 0; j < 2; j++) {
        int e = (tid + j * 256) * 8;
        bf16x8 w8 = *(const bf16x8*)(pw + e);
        float4 xa = *(const float4*)(px + e);
        float4 xb = *(const float4*)(px + e + 4);
        mx = fmaxf(mx, bf2f(w8[0]) * A + B + xa.x);
        mx = fmaxf(mx, bf2f(w8[1]) * A + B + xa.y);
        mx = fmaxf(mx, bf2f(w8[2]) * A + B + xa.z);
        mx = fmaxf(mx, bf2f(w8[3]) * A + B + xa.w);
        mx = fmaxf(mx, bf2f(w8[4]) * A + B + xb.x);
        mx = fmaxf(mx, bf2f(w8[5]) * A + B + xb.y);
        mx = fmaxf(mx, bf2f(w8[6]) * A + B + xb.z);
        mx = fmaxf(mx, bf2f(w8[7]) * A + B + xb.w);
    }
    #pragma unroll
    for (int off = 1; off < 64; off <<= 1) mx = fmaxf(mx, __shfl_xor(mx, off));
    __shared__ float red[4];
    if ((tid & 63) == 0) red[tid >> 6] = mx;
    __syncthreads();
    if (tid == 0)
        outp[b * 256 + o] = fmaxf(fmaxf(red[0], red[1]), fmaxf(red[2], red[3]));
}

extern "C" void kernel_launch(void* const* d_in, const int* in_sizes, int n_in,
                              void* d_out, int out_size, void* d_ws, size_t ws_size,
                              hipStream_t stream) {
    const float* x     = (const float*)d_in[0];
    const float* Wg    = (const float*)d_in[1];
    const float* bg    = (const float*)d_in[2];
    const float* Wt    = (const float*)d_in[3];
    const float* bt    = (const float*)d_in[4];
    const float* Wp    = (const float*)d_in[5];
    const float* bp    = (const float*)d_in[6];
    const float* Ww    = (const float*)d_in[7];
    const float* bw    = (const float*)d_in[8];
    const float* gamma = (const float*)d_in[9];
    const float* beta  = (const float*)d_in[10];
    float* outp = (float*)d_out;

    char* ws = (char*)d_ws;
    size_t off = 0;
    auto alloc = [&](size_t bytes) -> void* {
        void* p = ws + off;
        off = (off + bytes + 255) & ~(size_t)255;
        return p;
    };
    short* W_all = (short*)alloc((size_t)384 * 256 * 2);
    short* Ww16  = (short*)alloc((size_t)256 * 128 * 2);
    float* b_all = (float*)alloc((size_t)384 * 4);
    short* Out   = (short*)alloc((size_t)8 * 4096 * 384 * 2);
    short* Kmat  = (short*)alloc((size_t)8 * 1024 * 128 * 2);
    short* Vmat  = (short*)alloc((size_t)8 * 128 * 1024 * 2);
    short* Ybuf  = (short*)alloc((size_t)8 * 4096 * 128 * 2);
    short* wy    = (short*)alloc((size_t)8 * 256 * 4096 * 2);
    float* stats = (float*)alloc((size_t)256 * 2 * 4);
    float* ms    = (float*)alloc((size_t)256 * 2 * 4);

    hipMemsetAsync(stats, 0, 256 * 2 * 4, stream);

    k0_prep<<<512, 256, 0, stream>>>(Wg, Wt, Wp, bg, bt, bp, Ww, W_all, Ww16, b_all);
    k1_conv<<<dim3(32, 3, 8), 256, 0, stream>>>(x, W_all, b_all, Out);
    k2a_poolK<<<512, 256, 0, stream>>>(Out, Kmat);
    k2b_poolV<<<256, 256, 0, stream>>>(Out, Vmat);
    k3_attn<<<512, 256, 0, stream>>>(Out, Kmat, Vmat, Ybuf);
    k4_wy<<<dim3(16, 4, 8), 256, 0, stream>>>(Ww16, Ybuf, bw, wy, stats);
    k4b_stats<<<1, 256, 0, stream>>>(stats, ms);
    k5_bnmax<<<2048, 256, 0, stream>>>(wy, x, ms, gamma, beta, outp);
}